// Round 6
// baseline (333.344 us; speedup 1.0000x reference)
//
#include <hip/hip_runtime.h>

// ---------------------------------------------------------------------------
// BEV encoder: bucketed points->BEV (LDS-aggregated) + 3x conv-BN-ReLU
// Conv v3: SGPR weights + split-K occupancy + BN/ReLU fused into staging.
// ---------------------------------------------------------------------------

constexpr int BEVW = 250;
constexpr int SZC  = BEVW * BEVW;     // 62500 cells
constexpr int NB   = 512;             // blocks in bucket pass
constexpr int PPT  = 16;              // points/thread/chunk
constexpr int CHUNK = 256 * PPT;      // 4096
constexpr int NBKT = 100;             // 10x10 tiles of 25x25 cells
constexpr int NCELL = 625;            // cells per bucket
constexpr int CAPB = 43008;           // records capacity per bucket
constexpr int NSL  = 8;               // bnstats slices per channel

__device__ __forceinline__ unsigned f2ord(float f) {
    unsigned u = __float_as_uint(f);
    return (u & 0x80000000u) ? ~u : (u | 0x80000000u);
}
__device__ __forceinline__ float ord2f(unsigned u) {
    unsigned b = (u & 0x80000000u) ? (u & 0x7FFFFFFFu) : ~u;
    return __uint_as_float(b);
}

// ---- zero bucket counters ------------------------------------------------
__global__ void k_initg(unsigned* __restrict__ gcnt) {
    if (threadIdx.x < 128) gcnt[threadIdx.x] = 0u;
}

// ---- pass B: bin points into bucket record arrays ------------------------
// rec = z_ord(32) | cell_local(10) | inten_q22(22)
__launch_bounds__(256)
__global__ void k_bucket(const float4* __restrict__ pts, int n,
                         unsigned long long* __restrict__ recs,
                         unsigned* __restrict__ gcnt) {
    __shared__ unsigned lcnt[NBKT];
    __shared__ unsigned lbase[NBKT];
    const int tid = threadIdx.x;
    if (tid < NBKT) lcnt[tid] = 0u;
    __syncthreads();

    const int ppb = (n + NB - 1) / NB;
    const int start = blockIdx.x * ppb;
    const int end = min(start + ppb, n);

    for (int c0 = start; c0 < end; c0 += CHUNK) {
        unsigned long long rec[PPT];
        int bkt[PPT];
        unsigned slot[PPT];
        unsigned vmask = 0u;
#pragma unroll
        for (int k = 0; k < PPT; ++k) {
            int p = c0 + k * 256 + tid;
            if (p >= end) continue;
            float4 q = pts[p];
            if (!(q.x >= -50.0f && q.x < 50.0f && q.y >= -50.0f && q.y < 50.0f))
                continue;
            // must match JAX/np f32 semantics: f32 add, f32 div, trunc, clip
            int xi = (int)((q.x + 50.0f) / 0.4f);
            int yi = (int)((q.y + 50.0f) / 0.4f);
            xi = min(max(xi, 0), BEVW - 1);
            yi = min(max(yi, 0), BEVW - 1);
            int b  = (yi / 25) * 10 + (xi / 25);
            int cl = (yi % 25) * 25 + (xi % 25);
            unsigned iq = (unsigned)(q.w * 4194304.0f);   // 2^22, q.w in [0,1)
            rec[k] = ((unsigned long long)f2ord(q.z) << 32) |
                     ((unsigned long long)(unsigned)cl << 22) | iq;
            bkt[k] = b;
            slot[k] = atomicAdd(&lcnt[b], 1u);
            vmask |= 1u << k;
        }
        __syncthreads();
        if (tid < NBKT) {
            unsigned c = lcnt[tid];
            if (c) lbase[tid] = atomicAdd(&gcnt[tid], c);
            lcnt[tid] = 0u;
        }
        __syncthreads();
#pragma unroll
        for (int k = 0; k < PPT; ++k) {
            if (!((vmask >> k) & 1u)) continue;
            unsigned idx = lbase[bkt[k]] + slot[k];
            if (idx < (unsigned)CAPB)
                recs[(size_t)bkt[k] * CAPB + idx] = rec[k];
        }
    }
}

// ---- pass C: per-bucket LDS reduction + fused finalize -------------------
__launch_bounds__(1024)
__global__ void k_reduce(const unsigned long long* __restrict__ recs,
                         const unsigned* __restrict__ gcnt,
                         float* __restrict__ bev) {
    __shared__ unsigned mxA[NCELL], mnA[NCELL], ctA[NCELL], siA[NCELL];
    const int b = blockIdx.x;
    for (int i = threadIdx.x; i < NCELL; i += 1024) {
        mxA[i] = 0u; mnA[i] = 0xFFFFFFFFu; ctA[i] = 0u; siA[i] = 0u;
    }
    __syncthreads();
    const unsigned nb = min(gcnt[b], (unsigned)CAPB);
    const unsigned long long* rb = recs + (size_t)b * CAPB;
    for (unsigned i = threadIdx.x; i < nb; i += 1024) {
        unsigned long long r = rb[i];
        unsigned zo = (unsigned)(r >> 32);
        unsigned cl = ((unsigned)(r >> 22)) & 0x3FFu;
        unsigned iq = (unsigned)r & 0x3FFFFFu;
        atomicMax(&mxA[cl], zo);
        atomicMin(&mnA[cl], zo);
        atomicAdd(&ctA[cl], 1u);
        atomicAdd(&siA[cl], iq);
    }
    __syncthreads();
    const int tx = b % 10, ty = b / 10;
    for (int i = threadIdx.x; i < NCELL; i += 1024) {
        int cy = ty * 25 + i / 25, cx = tx * 25 + i % 25;
        int cell = cy * BEVW + cx;
        unsigned c = ctA[i];
        bool has = c > 0u;
        float dn = (float)c;
        float isum = (float)siA[i] * (1.0f / 4194304.0f);
        bev[0 * SZC + cell] = has ? ord2f(mxA[i]) : 0.0f;
        bev[1 * SZC + cell] = has ? ord2f(mnA[i]) : 0.0f;
        bev[2 * SZC + cell] = log1pf(dn);
        bev[3 * SZC + cell] = has ? isum / dn : 0.0f;
    }
}

// ---- weight transpose: w[oc][ic][3][3] -> wt[ic][k][oc] ------------------
__global__ void k_wt(const float* __restrict__ w, float* __restrict__ wt,
                     int CIN, int COUT) {
    int i = blockIdx.x * blockDim.x + threadIdx.x;
    if (i >= COUT * CIN * 9) return;
    int oc = i / (CIN * 9);
    int r  = i % (CIN * 9);
    int ic = r / 9, k = r % 9;
    wt[(ic * 9 + k) * COUT + oc] = w[i];
}

// ---- conv 3x3 SAME; SGPR weights; optional split-K / fused BN+ReLU -------
// ina/inb: [CINtot][250][250] raw conv outputs of prev layer (summed if SUM2),
// BN+ReLU applied during staging if FUSE_BN. wt: [CINtot][9][COUT].
// SPLIT: grid.z in {0,1} selects ic half [z*CINH, (z+1)*CINH); z==1 -> outb,
// bias only added by z==0 so partials sum to conv+bias.
template <int CINH, int COUT, int ICB, int OCG, bool FUSE_BN, bool SUM2, bool SPLIT>
__launch_bounds__(256)
__global__ void k_conv(const float* __restrict__ ina, const float* __restrict__ inb,
                       const float* __restrict__ wt, const float* __restrict__ bias,
                       const float* __restrict__ stats, const float* __restrict__ g,
                       const float* __restrict__ beta,
                       float* __restrict__ outa, float* __restrict__ outb) {
    __shared__ float s_in[ICB][18][18];

    const int tid = threadIdx.x;
    const int px = tid & 15, py = tid >> 4;
    const int tile = blockIdx.x;              // 0..255
    const int tx = (tile & 15) * 16, ty = (tile >> 4) * 16;
    const int oc0 = blockIdx.y * OCG;
    const int z = SPLIT ? blockIdx.z : 0;
    const int icB = z * CINH;
    float* out = (SPLIT && z) ? outb : outa;

    float acc[OCG];
#pragma unroll
    for (int o = 0; o < OCG; ++o) acc[o] = 0.0f;

    for (int ic0 = 0; ic0 < CINH; ic0 += ICB) {
        __syncthreads();
        // stage input tile with halo; fuse prev-layer partial-sum + BN + ReLU
        for (int e = tid; e < ICB * 18 * 18; e += 256) {
            int c = e / 324, r = (e % 324) / 18, q = e % 18;
            int cg = icB + ic0 + c;
            int gy = ty - 1 + r, gx = tx - 1 + q;
            float v = 0.0f;
            if (gy >= 0 && gy < BEVW && gx >= 0 && gx < BEVW) {
                size_t idx = (size_t)cg * SZC + gy * BEVW + gx;
                v = ina[idx];
                if (SUM2) v += inb[idx];
                if (FUSE_BN) {
                    float t = (v - stats[2 * cg]) * stats[2 * cg + 1] * g[cg] + beta[cg];
                    v = t > 0.0f ? t : 0.0f;
                }
            }
            s_in[c][r][q] = v;
        }
        __syncthreads();

#pragma unroll 2
        for (int icl = 0; icl < ICB; ++icl) {
#pragma unroll
            for (int k = 0; k < 9; ++k) {
                float v = s_in[icl][py + k / 3][px + k % 3];
                // block-uniform address -> scalar loads into SGPRs
                const float* wk = wt + ((size_t)((icB + ic0 + icl) * 9 + k) * COUT + oc0);
#pragma unroll
                for (int j = 0; j < OCG; ++j)
                    acc[j] = fmaf(v, wk[j], acc[j]);
            }
        }
    }

    int ox = tx + px, oy = ty + py;
    if (ox < BEVW && oy < BEVW) {
        const bool addb = (!SPLIT) || (z == 0);
#pragma unroll
        for (int o = 0; o < OCG; ++o)
            out[(oc0 + o) * SZC + oy * BEVW + ox] = acc[o] + (addb ? bias[oc0 + o] : 0.0f);
    }
}

// ---- BN stats, two stage (optional partial-sum input) --------------------
__global__ void k_bnstats1(const float* __restrict__ ya, const float* __restrict__ yb,
                           double* __restrict__ part) {
    const int c = blockIdx.x, s = blockIdx.y;
    const int lo = s * ((SZC + NSL - 1) / NSL);
    const int hi = min(lo + (SZC + NSL - 1) / NSL, SZC);
    const float* pa = ya + (size_t)c * SZC;
    const float* pb = yb ? yb + (size_t)c * SZC : nullptr;
    double sm = 0.0, s2 = 0.0;
    for (int i = lo + threadIdx.x; i < hi; i += 256) {
        float v = pa[i];
        if (pb) v += pb[i];
        sm += (double)v;
        s2 += (double)v * (double)v;
    }
    for (int off = 32; off; off >>= 1) {
        sm += __shfl_down(sm, off);
        s2 += __shfl_down(s2, off);
    }
    __shared__ double sh[8];
    int wid = threadIdx.x >> 6;
    if ((threadIdx.x & 63) == 0) { sh[wid * 2] = sm; sh[wid * 2 + 1] = s2; }
    __syncthreads();
    if (threadIdx.x == 0) {
        double S = 0.0, S2 = 0.0;
        for (int wv = 0; wv < 4; ++wv) { S += sh[wv * 2]; S2 += sh[wv * 2 + 1]; }
        part[(c * NSL + s) * 2]     = S;
        part[(c * NSL + s) * 2 + 1] = S2;
    }
}

__global__ void k_bnstats2(const double* __restrict__ part, float* __restrict__ stats) {
    int c = threadIdx.x;   // blockDim.x == C
    double S = 0.0, S2 = 0.0;
    for (int s = 0; s < NSL; ++s) {
        S  += part[(c * NSL + s) * 2];
        S2 += part[(c * NSL + s) * 2 + 1];
    }
    double mu  = S / (double)SZC;
    double var = S2 / (double)SZC - mu * mu;
    stats[c * 2]     = (float)mu;
    stats[c * 2 + 1] = (float)(1.0 / sqrt(var + 1e-5));
}

// ---- final BN apply + ReLU (optional partial-sum input) ------------------
__global__ void k_bnreluS(const float* __restrict__ ya, const float* __restrict__ yb,
                          const float* __restrict__ stats, const float* __restrict__ g,
                          const float* __restrict__ beta, float* __restrict__ out) {
    int c = blockIdx.y;
    int i = blockIdx.x * blockDim.x + threadIdx.x;
    if (i >= SZC) return;
    float mu = stats[c * 2], rs = stats[c * 2 + 1];
    size_t idx = (size_t)c * SZC + i;
    float v = ya[idx];
    if (yb) v += yb[idx];
    v = (v - mu) * rs * g[c] + beta[c];
    out[idx] = v > 0.0f ? v : 0.0f;
}

// ---------------------------------------------------------------------------
extern "C" void kernel_launch(void* const* d_in, const int* in_sizes, int n_in,
                              void* d_out, int out_size, void* d_ws, size_t ws_size,
                              hipStream_t stream) {
    const float4* pts = (const float4*)d_in[0];
    const float* w1 = (const float*)d_in[1];
    const float* b1 = (const float*)d_in[2];
    const float* g1 = (const float*)d_in[3];
    const float* be1 = (const float*)d_in[4];
    const float* w2 = (const float*)d_in[5];
    const float* b2 = (const float*)d_in[6];
    const float* g2 = (const float*)d_in[7];
    const float* be2 = (const float*)d_in[8];
    const float* w3 = (const float*)d_in[9];
    const float* b3 = (const float*)d_in[10];
    const float* g3 = (const float*)d_in[11];
    const float* be3 = (const float*)d_in[12];

    float* ws = (float*)d_ws;
    const size_t wsf = ws_size / 4;

    // --- fixed tail at end of workspace (308944 floats) ---
    constexpr size_t TAILF = 128 + 250000 + 64 + 128 + 128 + 2048 + 1152 + 18432 + 36864;
    float* tail = ws + (wsf - TAILF);
    unsigned* gcnt = (unsigned*)tail;
    float* bev = tail + 128;
    float* st1 = bev + 4 * SZC;
    float* st2 = st1 + 64;
    float* st3 = st2 + 128;
    float* pst = st3 + 128;
    double* bnpart = (double*)pst;            // 2048 floats
    float* wt1 = pst + 2048;                  // 32*4*9   = 1152
    float* wt2 = wt1 + 1152;                  // 64*32*9  = 18432
    float* wt3 = wt2 + 18432;                 // 64*64*9  = 36864

    // --- dynamic region [0, tailF): recs, then activations (recs dead) ---
    const size_t tailF = wsf - TAILF;
    unsigned long long* recs = (unsigned long long*)ws;   // 8,601,600 floats
    float* y1  = ws;                                      // 2M floats
    float* y2a = ws + 2000000;                            // 4M floats
    const bool split2 = tailF >= 14000000ULL;
    const bool split3 = tailF >= 10000000ULL;
    float* y2b  = split2 ? ws + 6000000 : nullptr;        // 4M floats
    float* outb = split3 ? (split2 ? ws + 10000000 : ws + 6000000) : nullptr;
    float* outa = (float*)d_out;

    int n = in_sizes[0] / 4;                              // 5,000,000 points
    const int cellBlocks = (SZC + 255) / 256;

    // weight transposes
    k_wt<<<(32 * 4 * 9 + 255) / 256, 256, 0, stream>>>(w1, wt1, 4, 32);
    k_wt<<<(64 * 32 * 9 + 255) / 256, 256, 0, stream>>>(w2, wt2, 32, 64);
    k_wt<<<(64 * 64 * 9 + 255) / 256, 256, 0, stream>>>(w3, wt3, 64, 64);

    // points -> BEV
    k_initg<<<1, 128, 0, stream>>>(gcnt);
    k_bucket<<<NB, 256, 0, stream>>>(pts, n, recs, gcnt);
    k_reduce<<<NBKT, 1024, 0, stream>>>(recs, gcnt, bev);

    // layer 1: 4 -> 32 (raw conv out; BN fused into conv2 staging)
    k_conv<4, 32, 4, 16, false, false, false>
        <<<dim3(256, 2, 1), 256, 0, stream>>>(bev, nullptr, wt1, b1,
                                              nullptr, nullptr, nullptr, y1, nullptr);
    k_bnstats1<<<dim3(32, NSL), 256, 0, stream>>>(y1, nullptr, bnpart);
    k_bnstats2<<<1, 32, 0, stream>>>(bnpart, st1);

    // layer 2: 32 -> 64 (stage applies BN1+ReLU; split-K if workspace allows)
    if (split2)
        k_conv<16, 64, 8, 16, true, false, true>
            <<<dim3(256, 4, 2), 256, 0, stream>>>(y1, nullptr, wt2, b2,
                                                  st1, g1, be1, y2a, y2b);
    else
        k_conv<32, 64, 8, 16, true, false, false>
            <<<dim3(256, 4, 1), 256, 0, stream>>>(y1, nullptr, wt2, b2,
                                                  st1, g1, be1, y2a, nullptr);
    k_bnstats1<<<dim3(64, NSL), 256, 0, stream>>>(y2a, y2b, bnpart);
    k_bnstats2<<<1, 64, 0, stream>>>(bnpart, st2);

    // layer 3: 64 -> 64 (stage sums y2 partials + BN2+ReLU; split-K)
    if (split3) {
        if (split2)
            k_conv<32, 64, 8, 16, true, true, true>
                <<<dim3(256, 4, 2), 256, 0, stream>>>(y2a, y2b, wt3, b3,
                                                      st2, g2, be2, outa, outb);
        else
            k_conv<32, 64, 8, 16, true, false, true>
                <<<dim3(256, 4, 2), 256, 0, stream>>>(y2a, nullptr, wt3, b3,
                                                      st2, g2, be2, outa, outb);
    } else {
        k_conv<64, 64, 8, 16, true, false, false>
            <<<dim3(256, 4, 1), 256, 0, stream>>>(y2a, nullptr, wt3, b3,
                                                  st2, g2, be2, outa, nullptr);
    }
    k_bnstats1<<<dim3(64, NSL), 256, 0, stream>>>(outa, outb, bnpart);
    k_bnstats2<<<1, 64, 0, stream>>>(bnpart, st3);

    // final BN3 + ReLU -> d_out
    k_bnreluS<<<dim3(cellBlocks, 64), 256, 0, stream>>>(outa, outb, st3, g3, be3,
                                                        (float*)d_out);
}